// Round 9
// baseline (567.432 us; speedup 1.0000x reference)
//
#include <hip/hip_runtime.h>
#include <hip/hip_bf16.h>
#include <math.h>

// ---------------------------------------------------------------------------
// GraphSAGE 3-layer + classifier + log_softmax.  Round 9.
//  - transform v3: thread owns output feature f, computes BOTH P[f],Q[f].
//    Weights in LDS as interleaved float2 (stride-1 b64, conflict-free);
//    64-node x-tile in LDS (broadcast b128).  8 FMA per weight read, 8 acc
//    chains, ~48 VGPR -> no rematerialization (round-8 lesson: VGPR_Count=52
//    proved w[64] never stayed resident).
//  - CSR pairs packed into one int: (src<<8)|local_dst  (halves scatter IO).
//  - bf16 P gather + bucket CSR otherwise unchanged.
// ---------------------------------------------------------------------------

#define BSHIFT 8
#define BUCKET 256
#define MAXB 512
#define SCAT_EDGES 8192
#define TROWS 64

__global__ __launch_bounds__(256) void hist_kernel(const int* __restrict__ dst,
                                                   int* __restrict__ ghist,
                                                   int E, int nbuck) {
    __shared__ int lh[MAXB];
    int t = threadIdx.x;
    lh[t] = 0; lh[t + 256] = 0;
    __syncthreads();
    int start = blockIdx.x * SCAT_EDGES;
    int end = min(E, start + SCAT_EDGES);
    for (int e = start + t; e < end; e += 256)
        atomicAdd(&lh[dst[e] >> BSHIFT], 1);
    __syncthreads();
    for (int b = t; b < nbuck; b += 256)
        if (lh[b]) atomicAdd(&ghist[b], lh[b]);
}

__global__ __launch_bounds__(512) void scanb_kernel(const int* __restrict__ ghist,
                                                    int* __restrict__ bbase,
                                                    int* __restrict__ gcur,
                                                    int nbuck, int E) {
    __shared__ int s[MAXB];
    int t = threadIdx.x;
    int v = (t < nbuck) ? ghist[t] : 0;
    s[t] = v;
    __syncthreads();
    for (int off = 1; off < MAXB; off <<= 1) {
        int u = (t >= off) ? s[t - off] : 0;
        __syncthreads();
        s[t] += u;
        __syncthreads();
    }
    int excl = s[t] - v;
    if (t < nbuck) { bbase[t] = excl; gcur[t] = excl; }
    if (t == 0) bbase[nbuck] = E;
}

__global__ __launch_bounds__(256) void scatter_kernel(const int* __restrict__ src,
                                                      const int* __restrict__ dst,
                                                      int* __restrict__ gcur,
                                                      unsigned int* __restrict__ pairs,
                                                      int E, int nbuck) {
    __shared__ int lh[MAXB];
    __shared__ int lbase[MAXB];
    __shared__ int lcur[MAXB];
    int t = threadIdx.x;
    lh[t] = 0; lh[t + 256] = 0;
    lcur[t] = 0; lcur[t + 256] = 0;
    __syncthreads();
    int start = blockIdx.x * SCAT_EDGES;
    int end = min(E, start + SCAT_EDGES);
    for (int e = start + t; e < end; e += 256)
        atomicAdd(&lh[dst[e] >> BSHIFT], 1);
    __syncthreads();
    for (int b = t; b < nbuck; b += 256)
        if (lh[b]) lbase[b] = atomicAdd(&gcur[b], lh[b]);
    __syncthreads();
    for (int e = start + t; e < end; e += 256) {
        int d = dst[e];
        int b = d >> BSHIFT;
        int slot = atomicAdd(&lcur[b], 1);
        pairs[lbase[b] + slot] = ((unsigned int)src[e] << BSHIFT) | (unsigned int)(d & (BUCKET - 1));
    }
}

__global__ __launch_bounds__(256) void build_kernel(const unsigned int* __restrict__ pairs,
                                                    const int* __restrict__ bbase,
                                                    int* __restrict__ rowptr,
                                                    int* __restrict__ col,
                                                    int n, int E) {
    __shared__ int ldeg[BUCKET];
    __shared__ int pre[BUCKET];
    __shared__ int cur[BUCKET];
    int t = threadIdx.x;
    int nbase = blockIdx.x << BSHIFT;
    int e0 = bbase[blockIdx.x], e1 = bbase[blockIdx.x + 1];
    ldeg[t] = 0; cur[t] = 0;
    __syncthreads();
    for (int e = e0 + t; e < e1; e += 256)
        atomicAdd(&ldeg[pairs[e] & (BUCKET - 1)], 1);
    __syncthreads();
    int v = ldeg[t];
    pre[t] = v;
    __syncthreads();
    for (int off = 1; off < 256; off <<= 1) {
        int u = (t >= off) ? pre[t - off] : 0;
        __syncthreads();
        pre[t] += u;
        __syncthreads();
    }
    int excl = pre[t] - v;
    __syncthreads();
    pre[t] = excl;
    __syncthreads();
    int node = nbase + t;
    if (node < n) rowptr[node] = e0 + excl;
    if (blockIdx.x == 0 && t == 0) rowptr[n] = E;
    for (int e = e0 + t; e < e1; e += 256) {
        unsigned int p = pairs[e];
        int l = (int)(p & (BUCKET - 1));
        int pos = atomicAdd(&cur[l], 1);
        col[e0 + pre[l] + pos] = (int)(p >> BSHIFT);
    }
}

// --- Dense transform v3: P[v]=in[v]@Wl (bf16), Q[v]=in[v]@Wr+bl (f32).
// Thread owns feature f (computes BOTH P,Q); weights in LDS as float2{wl,wr};
// 64-node x-tile in LDS read via wave-uniform broadcast b128; 4-row unroll,
// 8 accumulator chains.  In-place safe (in==Qh): block touches only its rows.
__global__ __launch_bounds__(256) void transform_kernel(
    const float* in, float* Qh, __hip_bfloat16* __restrict__ Pb,
    const float* __restrict__ Wl, const float* __restrict__ bl,
    const float* __restrict__ Wr, int n)
{
    __shared__ float4 tile[TROWS * 16];   // 16 KB: 64 nodes x 64 f32
    __shared__ float2 w2[64 * 64];        // 32 KB: {Wl[k][f], Wr[k][f]}
    int tid = threadIdx.x;
    int f = tid & 63, g = tid >> 6;       // 4 row-groups of 16 rows

    for (int i = tid; i < 64 * 64; i += 256) w2[i] = make_float2(Wl[i], Wr[i]);
    float bias = bl[f];

    int base = blockIdx.x * TROWS;
    int nvalid = n - base; if (nvalid > TROWS) nvalid = TROWS;
    const float4* srcp = (const float4*)(in + (size_t)base * 64);
    for (int i = tid; i < nvalid * 16; i += 256) tile[i] = srcp[i];
    __syncthreads();

    #pragma unroll
    for (int s = 0; s < 4; ++s) {
        int r0 = (g << 4) + (s << 2);
        float p0 = 0.f, p1 = 0.f, p2 = 0.f, p3 = 0.f;
        float q0 = bias, q1 = bias, q2 = bias, q3 = bias;
        #pragma unroll
        for (int kq = 0; kq < 16; ++kq) {
            float4 x0 = tile[(r0 + 0) * 16 + kq];
            float4 x1 = tile[(r0 + 1) * 16 + kq];
            float4 x2 = tile[(r0 + 2) * 16 + kq];
            float4 x3 = tile[(r0 + 3) * 16 + kq];
            #pragma unroll
            for (int j = 0; j < 4; ++j) {
                float2 ww = w2[(4 * kq + j) * 64 + f];
                float v0 = (&x0.x)[j], v1 = (&x1.x)[j];
                float v2 = (&x2.x)[j], v3 = (&x3.x)[j];
                p0 = fmaf(v0, ww.x, p0); q0 = fmaf(v0, ww.y, q0);
                p1 = fmaf(v1, ww.x, p1); q1 = fmaf(v1, ww.y, q1);
                p2 = fmaf(v2, ww.x, p2); q2 = fmaf(v2, ww.y, q2);
                p3 = fmaf(v3, ww.x, p3); q3 = fmaf(v3, ww.y, q3);
            }
        }
        int v = base + r0;
        if (v + 0 < n) { Pb[(size_t)(v + 0) * 64 + f] = __float2bfloat16(p0); Qh[(size_t)(v + 0) * 64 + f] = q0; }
        if (v + 1 < n) { Pb[(size_t)(v + 1) * 64 + f] = __float2bfloat16(p1); Qh[(size_t)(v + 1) * 64 + f] = q1; }
        if (v + 2 < n) { Pb[(size_t)(v + 2) * 64 + f] = __float2bfloat16(p2); Qh[(size_t)(v + 2) * 64 + f] = q2; }
        if (v + 3 < n) { Pb[(size_t)(v + 3) * 64 + f] = __float2bfloat16(p3); Qh[(size_t)(v + 3) * 64 + f] = q3; }
    }
}

// --- Pure-memory gather: h[v] = relu( mean_{s in N(v)} P[s] + Q[v] ) -> Qh[v].
__global__ __launch_bounds__(256) void gather_kernel(
    const __hip_bfloat16* __restrict__ Pb, float* __restrict__ Qh,
    const int* __restrict__ rowptr, const int* __restrict__ col, int n)
{
    int tid = threadIdx.x;
    int wid = tid >> 6, lane = tid & 63;
    int w = blockIdx.x * 4 + wid;
    int nw = gridDim.x * 4;
    for (int v = w; v < n; v += nw) {
        int s0 = rowptr[v], s1 = rowptr[v + 1];
        int deg = s1 - s0;
        float q = Qh[(size_t)v * 64 + lane];
        float acc = 0.f;
        for (int base = 0; base < deg; base += 64) {
            int rem = deg - base;
            int cnt = rem < 64 ? rem : 64;
            int ci = (lane < cnt) ? col[s0 + base + lane] : 0;
            int j = 0;
            for (; j + 8 <= cnt; j += 8) {
                int i0 = __shfl(ci, j + 0), i1 = __shfl(ci, j + 1);
                int i2 = __shfl(ci, j + 2), i3 = __shfl(ci, j + 3);
                int i4 = __shfl(ci, j + 4), i5 = __shfl(ci, j + 5);
                int i6 = __shfl(ci, j + 6), i7 = __shfl(ci, j + 7);
                float t0 = __bfloat162float(Pb[(size_t)i0 * 64 + lane]);
                float t1 = __bfloat162float(Pb[(size_t)i1 * 64 + lane]);
                float t2 = __bfloat162float(Pb[(size_t)i2 * 64 + lane]);
                float t3 = __bfloat162float(Pb[(size_t)i3 * 64 + lane]);
                float t4 = __bfloat162float(Pb[(size_t)i4 * 64 + lane]);
                float t5 = __bfloat162float(Pb[(size_t)i5 * 64 + lane]);
                float t6 = __bfloat162float(Pb[(size_t)i6 * 64 + lane]);
                float t7 = __bfloat162float(Pb[(size_t)i7 * 64 + lane]);
                acc += ((t0 + t1) + (t2 + t3)) + ((t4 + t5) + (t6 + t7));
            }
            for (; j + 4 <= cnt; j += 4) {
                int i0 = __shfl(ci, j + 0), i1 = __shfl(ci, j + 1);
                int i2 = __shfl(ci, j + 2), i3 = __shfl(ci, j + 3);
                float t0 = __bfloat162float(Pb[(size_t)i0 * 64 + lane]);
                float t1 = __bfloat162float(Pb[(size_t)i1 * 64 + lane]);
                float t2 = __bfloat162float(Pb[(size_t)i2 * 64 + lane]);
                float t3 = __bfloat162float(Pb[(size_t)i3 * 64 + lane]);
                acc += (t0 + t1) + (t2 + t3);
            }
            for (; j < cnt; ++j)
                acc += __bfloat162float(Pb[(size_t)__shfl(ci, j) * 64 + lane]);
        }
        float res = acc / fmaxf((float)deg, 1.0f) + q;
        Qh[(size_t)v * 64 + lane] = fmaxf(res, 0.f);
    }
}

// --- Classifier + log_softmax on h rows (stride 64). ---
__global__ __launch_bounds__(256) void cls_kernel(
    const float* __restrict__ h, const float* __restrict__ Wc,
    const float* __restrict__ bc, float* __restrict__ out, int n)
{
    __shared__ float sW[64 * 10];
    __shared__ float sb[16];
    __shared__ float srow[4][4][64];
    int tid = threadIdx.x;
    for (int i = tid; i < 640; i += 256) sW[i] = Wc[i];
    if (tid < 10) sb[tid] = bc[tid];
    __syncthreads();

    int wid = tid >> 6, lane = tid & 63;
    int grp = lane >> 4, l16 = lane & 15;
    int w = blockIdx.x * 4 + wid;
    int nw = gridDim.x * 4;
    int ngroups = (n + 3) >> 2;
    for (int g = w; g < ngroups; g += nw) {
        int v0 = g * 4;
        #pragma unroll
        for (int r = 0; r < 4; ++r) {
            int vv = v0 + r;
            if (vv < n) srow[wid][r][lane] = h[(size_t)vv * 64 + lane];
        }
        int v = v0 + grp;
        float z = -INFINITY;
        if (v < n && l16 < 10) {
            z = sb[l16];
            #pragma unroll
            for (int k = 0; k < 64; ++k)
                z += srow[wid][grp][k] * sW[k * 10 + l16];
        }
        float m = z;
        for (int off = 8; off > 0; off >>= 1)
            m = fmaxf(m, __shfl_xor(m, off, 16));
        float e = (l16 < 10 && v < n) ? expf(z - m) : 0.f;
        float ssum = e;
        for (int off = 8; off > 0; off >>= 1)
            ssum += __shfl_xor(ssum, off, 16);
        if (v < n && l16 < 10)
            out[(size_t)v * 10 + l16] = z - m - logf(ssum);
    }
}

extern "C" void kernel_launch(void* const* d_in, const int* in_sizes, int n_in,
                              void* d_out, int out_size, void* d_ws, size_t ws_size,
                              hipStream_t stream) {
    const float* x   = (const float*)d_in[0];
    const int*   ei  = (const int*)d_in[1];
    const float* Wl1 = (const float*)d_in[2];
    const float* bl1 = (const float*)d_in[3];
    const float* Wr1 = (const float*)d_in[4];
    const float* Wl2 = (const float*)d_in[5];
    const float* bl2 = (const float*)d_in[6];
    const float* Wr2 = (const float*)d_in[7];
    const float* Wl3 = (const float*)d_in[8];
    const float* bl3 = (const float*)d_in[9];
    const float* Wr3 = (const float*)d_in[10];
    const float* Wc  = (const float*)d_in[11];
    const float* bc  = (const float*)d_in[12];
    float* outp = (float*)d_out;

    int n = in_sizes[0] / 64;
    int E = in_sizes[1] / 2;
    const int* srcp = ei;
    const int* dstp = ei + E;
    int nbuck = (n + BUCKET - 1) >> BSHIFT;
    int SB = (E + SCAT_EDGES - 1) / SCAT_EDGES;
    int ntile = (n + TROWS - 1) / TROWS;

    char* ws = (char*)d_ws;
    size_t off = 0;
    auto alloc = [&](size_t bytes) -> void* {
        void* p = ws + off;
        off += bytes;
        off = (off + 255) & ~(size_t)255;
        return p;
    };
    int*   ghist  = (int*)alloc((size_t)MAXB * 4);
    int*   bbase  = (int*)alloc((size_t)(MAXB + 1) * 4);
    int*   gcur   = (int*)alloc((size_t)MAXB * 4);
    int*   rowptr = (int*)alloc((size_t)(n + 1) * 4);
    unsigned int* pairs = (unsigned int*)alloc((size_t)E * 4);
    int*   colv   = (int*)alloc((size_t)E * 4);
    __hip_bfloat16* Pb = (__hip_bfloat16*)alloc((size_t)n * 64 * 2);
    float* Qh     = (float*)alloc((size_t)n * 64 * 4);
    (void)ws_size; (void)n_in; (void)out_size;

    hipMemsetAsync(ghist, 0, (size_t)MAXB * 4, stream);

    hist_kernel<<<SB, 256, 0, stream>>>(dstp, ghist, E, nbuck);
    scanb_kernel<<<1, 512, 0, stream>>>(ghist, bbase, gcur, nbuck, E);
    scatter_kernel<<<SB, 256, 0, stream>>>(srcp, dstp, gcur, pairs, E, nbuck);
    build_kernel<<<nbuck, 256, 0, stream>>>(pairs, bbase, rowptr, colv, n, E);

    transform_kernel<<<ntile, 256, 0, stream>>>(x,  Qh, Pb, Wl1, bl1, Wr1, n);
    gather_kernel<<<2048, 256, 0, stream>>>(Pb, Qh, rowptr, colv, n);
    transform_kernel<<<ntile, 256, 0, stream>>>(Qh, Qh, Pb, Wl2, bl2, Wr2, n);
    gather_kernel<<<2048, 256, 0, stream>>>(Pb, Qh, rowptr, colv, n);
    transform_kernel<<<ntile, 256, 0, stream>>>(Qh, Qh, Pb, Wl3, bl3, Wr3, n);
    gather_kernel<<<2048, 256, 0, stream>>>(Pb, Qh, rowptr, colv, n);

    cls_kernel<<<1024, 256, 0, stream>>>(Qh, Wc, bc, outp, n);
}